// Round 6
// baseline (87.962 us; speedup 1.0000x reference)
//
#include <hip/hip_runtime.h>

// out[(i*7+k)*C + c] = bias[(i*7+k)*C + c] + sum_j x[c*49 + j*7 + i] * weight[(j*7+k)*C + c]
//
// Memory-bound fp32, ~402 MB logical traffic; mixed-stream ceiling ~6.3 TB/s
// (m13 float4-copy) -> floor ~64 us. R4 = 73 us. R5 (896-thr) regressed.
// R6 = R4 structure with ALL global loads hoisted to the top:
//   7 stage-f4 -> 7 w-f4 -> 7 b-f4, then LDS scatter (vmcnt in-order waits
//   only drain the stage loads, leaving w/b in flight across the barrier),
//   then a pure LDS+FMA+store i-loop with no long-latency dependencies.
// This removes R4's per-i serial {b-load -> fma -> store} chains (~6300
// dependent cycles/block).
//
// Layout: thread (q,kk) owns channels cbase+4q..+3, one k. w/b/out are f4
// (16 B/lane coalesced). x staged transposed in LDS, XOR-swizzled
// (g=(pos>>2)&7) so scatter-writes and row reads are conflict-light.
// out uses nontemporal f4 stores (write-once stream; keeps inputs L3-hot).

typedef float f4 __attribute__((ext_vector_type(4)));

constexpr int C    = 524288;
constexpr int HW   = 49;
constexpr int CHB  = 256;              // channels per block
constexpr int NTHR = 64 * 7;           // 448 threads = 7 waves
constexpr int RS   = CHB;              // LDS row stride (dwords) per pos
constexpr int NF4  = CHB * HW / 4;     // 3136 float4 per block slab

__global__ __launch_bounds__(NTHR)
void mylinear_kernel(const float* __restrict__ x,
                     const float* __restrict__ w,
                     const float* __restrict__ b,
                     float* __restrict__ out) {
    __shared__ float xs[HW * CHB];     // 50176 B

    const int tid   = threadIdx.y * 64 + threadIdx.x;
    const int cbase = blockIdx.x * CHB;
    const int q     = threadIdx.x;     // quad 0..63
    const int kk    = threadIdx.y;     // 0..6
    const int c     = cbase + (q << 2);

    // ---- phase 0: issue ALL global loads back-to-back ----
    // stage loads first (7 f4), then w (7 f4), then b (7 f4). The ds_writes
    // below consume only the stage loads; the compiler's in-order vmcnt wait
    // leaves the 14 w/b loads outstanding across the barrier.
    const f4* __restrict__ xsrc = reinterpret_cast<const f4*>(x + (size_t)cbase * HW);
    f4 stg[7];
#pragma unroll
    for (int it = 0; it < 7; ++it) stg[it] = xsrc[it * NTHR + tid];

    f4 wq[7];
#pragma unroll
    for (int j = 0; j < 7; ++j)
        wq[j] = *reinterpret_cast<const f4*>(w + (size_t)(j * 7 + kk) * C + c);

    f4 bacc[7];
#pragma unroll
    for (int i = 0; i < 7; ++i)
        bacc[i] = *reinterpret_cast<const f4*>(b + (size_t)(i * 7 + kk) * C + c);

    // ---- phase 1: LDS transpose scatter (XOR-swizzled) ----
#pragma unroll
    for (int it = 0; it < 7; ++it) {
        const int idx = it * NTHR + tid;
#pragma unroll
        for (int t = 0; t < 4; ++t) {
            const int e   = idx * 4 + t;
            const int cl  = e / HW;            // local channel 0..255
            const int pos = e % HW;            // 0..48
            const int g   = (pos >> 2) & 7;
            const int sl  = (cl >> 2) ^ g;     // swizzled float4 slot
            xs[pos * RS + (sl << 2 | (cl & 3))] = stg[it][t];
        }
    }
    __syncthreads();

    // ---- phase 2: pure LDS + FMA + nt-store ----
#pragma unroll
    for (int i = 0; i < 7; ++i) {
        f4 xv[7];
#pragma unroll
        for (int j = 0; j < 7; ++j) {
            const int pos = j * 7 + i;
            const int g   = (pos >> 2) & 7;
            xv[j] = *reinterpret_cast<const f4*>(xs + pos * RS + ((q ^ g) << 2));
        }
        f4 acc = bacc[i];
#pragma unroll
        for (int j = 0; j < 7; ++j) {
            acc.x = fmaf(xv[j].x, wq[j].x, acc.x);
            acc.y = fmaf(xv[j].y, wq[j].y, acc.y);
            acc.z = fmaf(xv[j].z, wq[j].z, acc.z);
            acc.w = fmaf(xv[j].w, wq[j].w, acc.w);
        }
        __builtin_nontemporal_store(acc,
            reinterpret_cast<f4*>(out + (size_t)(i * 7 + kk) * C + c));
    }
}

extern "C" void kernel_launch(void* const* d_in, const int* in_sizes, int n_in,
                              void* d_out, int out_size, void* d_ws, size_t ws_size,
                              hipStream_t stream) {
    const float* x = (const float*)d_in[0];
    const float* w = (const float*)d_in[1];
    const float* b = (const float*)d_in[2];
    float* out     = (float*)d_out;

    dim3 grid(C / CHB), block(64, 7);
    mylinear_kernel<<<grid, block, 0, stream>>>(x, w, b, out);
}

// Round 7
// 72.176 us; speedup vs baseline: 1.2187x; 1.2187x over previous
//
#include <hip/hip_runtime.h>

// out[(i*7+k)*C + c] = bias[(i*7+k)*C + c] + sum_j x[c*49 + j*7 + i] * weight[(j*7+k)*C + c]
//
// Memory-bound fp32, ~402 MB logical traffic. Best so far: R4 = 73 us
// (5.5 TB/s logical; HBM only 3.4 TB/s -- L3 absorbs half the reads).
// R5 (bigger block) and R6 (full pre-barrier hoist) both regressed by
// confounded changes. R7 = R4 byte-identical EXCEPT one-deep software
// prefetch of the bias load in the i-loop: issue b[i+1] at the top of
// iteration i, consume b[i] loaded previously. This breaks the 7 serial
// {b-load -> fma -> store} latency chains (~3500+ dependent cycles/wave)
// that R4 paid after the barrier, at a cost of ~8 VGPRs.
//
// Layout: thread (q,kk) owns channels cbase+4q..+3 for one k. w/b/out are
// f4 (16 B/lane coalesced). x staged transposed in LDS, XOR-swizzled
// (g=(pos>>2)&7): scatter-writes and row-broadcast f4 reads conflict-light
// (measured 392 conflict-cycles/block). out uses nontemporal f4 stores.

typedef float f4 __attribute__((ext_vector_type(4)));

constexpr int C    = 524288;
constexpr int HW   = 49;
constexpr int CHB  = 256;              // channels per block
constexpr int NTHR = 64 * 7;           // 448 threads = 7 waves
constexpr int RS   = CHB;              // LDS row stride (dwords) per pos
constexpr int NF4  = CHB * HW / 4;     // 3136 float4 per block slab

__global__ __launch_bounds__(NTHR)
void mylinear_kernel(const float* __restrict__ x,
                     const float* __restrict__ w,
                     const float* __restrict__ b,
                     float* __restrict__ out) {
    __shared__ float xs[HW * CHB];     // 50176 B

    const int tid   = threadIdx.y * 64 + threadIdx.x;
    const int cbase = blockIdx.x * CHB;

    // ---- stage x slab, transposing channel-major -> pos-major with XOR swizzle ----
    const f4* __restrict__ xsrc = reinterpret_cast<const f4*>(x + (size_t)cbase * HW);
#pragma unroll
    for (int it = 0; it < NF4 / NTHR; ++it) {   // 3136/448 = 7 exact
        const int idx = it * NTHR + tid;
        const f4 v = xsrc[idx];
#pragma unroll
        for (int t = 0; t < 4; ++t) {
            const int e   = idx * 4 + t;
            const int cl  = e / HW;            // local channel 0..255
            const int pos = e % HW;            // 0..48
            const int g   = (pos >> 2) & 7;
            const int sl  = (cl >> 2) ^ g;     // swizzled float4 slot
            xs[pos * RS + (sl << 2 | (cl & 3))] = v[t];
        }
    }
    __syncthreads();

    // ---- compute: thread (q, kk) -> channels cbase+4q..+3, outputs p = i*7+kk ----
    const int q  = threadIdx.x;                // quad index 0..63
    const int kk = threadIdx.y;                // 0..6
    const int c  = cbase + (q << 2);

    f4 wq[7];
#pragma unroll
    for (int j = 0; j < 7; ++j)
        wq[j] = *reinterpret_cast<const f4*>(w + (size_t)(j * 7 + kk) * C + c);

    // one-deep bias prefetch pipeline
    f4 bcur = *reinterpret_cast<const f4*>(b + (size_t)(0 * 7 + kk) * C + c);

#pragma unroll
    for (int i = 0; i < 7; ++i) {
        f4 bnext;
        if (i < 6)
            bnext = *reinterpret_cast<const f4*>(b + (size_t)((i + 1) * 7 + kk) * C + c);

        f4 xv[7];
#pragma unroll
        for (int j = 0; j < 7; ++j) {
            const int pos = j * 7 + i;
            const int g   = (pos >> 2) & 7;
            xv[j] = *reinterpret_cast<const f4*>(xs + pos * RS + ((q ^ g) << 2));
        }
        f4 acc = bcur;
#pragma unroll
        for (int j = 0; j < 7; ++j) {
            acc.x = fmaf(xv[j].x, wq[j].x, acc.x);
            acc.y = fmaf(xv[j].y, wq[j].y, acc.y);
            acc.z = fmaf(xv[j].z, wq[j].z, acc.z);
            acc.w = fmaf(xv[j].w, wq[j].w, acc.w);
        }
        __builtin_nontemporal_store(acc,
            reinterpret_cast<f4*>(out + (size_t)(i * 7 + kk) * C + c));
        bcur = bnext;
    }
}

extern "C" void kernel_launch(void* const* d_in, const int* in_sizes, int n_in,
                              void* d_out, int out_size, void* d_ws, size_t ws_size,
                              hipStream_t stream) {
    const float* x = (const float*)d_in[0];
    const float* w = (const float*)d_in[1];
    const float* b = (const float*)d_in[2];
    float* out     = (float*)d_out;

    dim3 grid(C / CHB), block(64, 7);
    mylinear_kernel<<<grid, block, 0, stream>>>(x, w, b, out);
}